// Round 7
// baseline (159.059 us; speedup 1.0000x reference)
//
#include <hip/hip_runtime.h>
#include <math.h>

// CPC loss, MI355X. B=16 T=512 D=256, horizons {1,5,21}, 128 negatives, temp 0.07.
// *** DIAGNOSTIC ROUND: k_loss body repeated 4x (bit-identical output) so its
// *** per-dispatch duration (~4x35us) outranks the 45us harness fills and its
// *** counters (VALUBusy/Occupancy/FETCH) appear in the top-5 table. All other
// *** kernels byte-identical to the 104.26us round-6 build.
// ws: [0,4MB) az f16 | [4MB,+1MB) ani4 int4 | [5MB,+384KB) Wh f16 |
//     [5.375MB,+12MB) zp f16 | [17.375MB,+24KB) partials f32
// LESSON (r4/r5): one agent-scope done-counter atomic per block serializes
// retirement (~30ns/RMW x 6129 = ~185us). LESSON (r3): spin grid barriers idle
// the GPU (VALU 3.5%).
constexpr int Bc = 16, Tc = 512, Dc = 256, NNEGc = 128, BTc = Bc * Tc;
constexpr float TEMP_INV = 1.0f / 0.07f;
constexpr float SCALE4 = 21.875f;              // 7 / 0.32 clip
constexpr float QSCALE4 = TEMP_INV / (SCALE4 * SCALE4);
constexpr float FMAXL = TEMP_INV;              // algebraic softmax stabilizer
constexpr int GXL = 1022;                      // 8176/8 row-groups per horizon
constexpr int NPART = 3 * GXL;                 // 3066 partials

typedef __attribute__((ext_vector_type(8))) short short8;
typedef __attribute__((ext_vector_type(4))) float f32x4;
typedef __attribute__((ext_vector_type(4))) _Float16 f16x4;
typedef __attribute__((ext_vector_type(2))) _Float16 h2;

struct HP { int L, N, kh; float scale; long long nxOff; };
struct HP3 { HP h[3]; };

// DPP helpers (ctrl literal). quad_perm: xor1=0xB1, xor2=0x4E, bcast k=k*0x55.
#define DPP_I(x, ctrl) __builtin_amdgcn_update_dpp(0, (x), (ctrl), 0xF, 0xF, true)
#define FDPP_XOR1(x) __builtin_bit_cast(float, DPP_I(__builtin_bit_cast(int, (x)), 0xB1))
#define FDPP_XOR2(x) __builtin_bit_cast(float, DPP_I(__builtin_bit_cast(int, (x)), 0x4E))

__device__ inline unsigned packh2(float a, float b) {
    h2 p = {(_Float16)a, (_Float16)b};
    return __builtin_bit_cast(unsigned, p);
}
__device__ inline float dot2(unsigned a, unsigned b, float c) {
#if __has_builtin(__builtin_amdgcn_fdot2)
    return __builtin_amdgcn_fdot2(__builtin_bit_cast(h2, a), __builtin_bit_cast(h2, b), c, false);
#else
    h2 x = __builtin_bit_cast(h2, a), y = __builtin_bit_cast(h2, b);
    return c + (float)x.x * (float)y.x + (float)x.y * (float)y.y;
#endif
}
__device__ inline int sdot8(unsigned a, unsigned b, int c) {
#if __has_builtin(__builtin_amdgcn_sdot8)
    return __builtin_amdgcn_sdot8((int)a, (int)b, c, false);
#else
#pragma unroll
    for (int i = 0; i < 8; ++i) {
        int xa = ((int)(a << (28 - 4 * i))) >> 28;
        int xb = ((int)(b << (28 - 4 * i))) >> 28;
        c += xa * xb;
    }
    return c;
#endif
}
// 4 floats -> 4 signed int4 nibbles (clipped to +-7), packed low-nibble-first
__device__ inline unsigned q4x4(float a, float b, float c, float d) {
    int qa = (int)rintf(fminf(fmaxf(a * SCALE4, -7.0f), 7.0f));
    int qb = (int)rintf(fminf(fmaxf(b * SCALE4, -7.0f), 7.0f));
    int qc = (int)rintf(fminf(fmaxf(c * SCALE4, -7.0f), 7.0f));
    int qd = (int)rintf(fminf(fmaxf(d * SCALE4, -7.0f), 7.0f));
    return (qa & 0xF) | ((qb & 0xF) << 4) | ((qc & 0xF) << 8) | ((qd & 0xF) << 12);
}

// Normalize all BT rows -> az (f16, 512 B/row) + ani4 (int4, 128 B/row);
// first 96 blocks convert W to f16.
__global__ __launch_bounds__(256) void k_norm(const float* __restrict__ z,
                                              const float* __restrict__ preds,
                                              unsigned* __restrict__ az,
                                              unsigned short* __restrict__ ani4,
                                              unsigned* __restrict__ Wh) {
    if (blockIdx.x < 96) {
        int base = blockIdx.x * 2048 + threadIdx.x * 8;
        float4 w0 = reinterpret_cast<const float4*>(preds + base)[0];
        float4 w1 = reinterpret_cast<const float4*>(preds + base)[1];
        uint4 o;
        o.x = packh2(w0.x, w0.y); o.y = packh2(w0.z, w0.w);
        o.z = packh2(w1.x, w1.y); o.w = packh2(w1.z, w1.w);
        reinterpret_cast<uint4*>(Wh)[blockIdx.x * 256 + threadIdx.x] = o;
    }
    int wid = threadIdx.x >> 6, lane = threadIdx.x & 63;
    int row = blockIdx.x * 4 + wid;
    float4 v = reinterpret_cast<const float4*>(z)[row * 64 + lane];
    float s = v.x * v.x + v.y * v.y + v.z * v.z + v.w * v.w;
#pragma unroll
    for (int off = 32; off; off >>= 1) s += __shfl_xor(s, off, 64);
    float inv = 1.0f / fmaxf(sqrtf(s), 1e-12f);
    float a = v.x * inv, b = v.y * inv, c = v.z * inv, d = v.w * inv;
    reinterpret_cast<uint2*>(az)[row * 64 + lane] = make_uint2(packh2(a, b), packh2(c, d));
    ani4[row * 64 + lane] = (unsigned short)q4x4(a, b, c, d);
}

// LDS-tiled f16 MFMA GEMM, XOR-swizzled LDS. Block 64x64, K=256, 4 waves.
__global__ __launch_bounds__(256) void k_gemm(const unsigned* __restrict__ az,
                                              const unsigned* __restrict__ Wh,
                                              _Float16* __restrict__ zp) {
    __shared__ uint4 As[2048];
    __shared__ uint4 Bs[2048];
    int wave = threadIdx.x >> 6, lane = threadIdx.x & 63;
    int t = threadIdx.x;
    int m0 = blockIdx.x * 64, g0 = blockIdx.y * 64;
    const uint4* A4 = reinterpret_cast<const uint4*>(az) + (size_t)m0 * 32;
    const uint4* B4 = reinterpret_cast<const uint4*>(Wh) + (size_t)g0 * 32;
#pragma unroll
    for (int i = 0; i < 8; ++i) {
        int f = i * 256 + t;
        int r = f >> 5, c = f & 31;
        int sw = r * 32 + ((c ^ r) & 31);
        As[sw] = A4[f];
        Bs[sw] = B4[f];
    }
    __syncthreads();
    int mrow = lane & 15, kq = lane >> 4;
    f32x4 acc[4] = {f32x4{0,0,0,0}, f32x4{0,0,0,0}, f32x4{0,0,0,0}, f32x4{0,0,0,0}};
    int arow = wave * 16 + mrow;
#pragma unroll
    for (int kb = 0; kb < 8; ++kb) {
        int col = kb * 4 + kq;
        uint4 ua = As[arow * 32 + ((col ^ arow) & 31)];
        short8 a = __builtin_bit_cast(short8, ua);
#pragma unroll
        for (int nt = 0; nt < 4; ++nt) {
            int brow = nt * 16 + mrow;
            uint4 ub = Bs[brow * 32 + ((col ^ brow) & 31)];
            acc[nt] = __builtin_amdgcn_mfma_f32_16x16x32_f16(
                a, __builtin_bit_cast(short8, ub), acc[nt], 0, 0, 0);
        }
    }
#pragma unroll
    for (int nt = 0; nt < 4; ++nt) {
        int g = g0 + nt * 16 + mrow;
        int h = g >> 8, e = g & 255;
        _Float16* dst = zp + ((size_t)h * BTc + m0 + wave * 16 + kq * 4) * Dc + e;
#pragma unroll
        for (int r = 0; r < 4; ++r) dst[(size_t)r * Dc] = (_Float16)acc[nt][r];
    }
}

// Per-row loss body (fully inlined twice per wave). 4-lane-group INT4 gather
// (16 gather instrs/row, every 64 B line fully consumed), DPP quad reductions,
// packed dual-logit word (integer-exact: per-lane field [960,7232], 4-lane
// sum <= 28928 < 2^16, bias totals 16384).
__device__ __forceinline__ float row_loss(const uint4* __restrict__ ni4,
                                          uint4* __restrict__ zq,
                                          int lane, int s,
                                          int ja, int jb,
                                          f16x4 hv, uint2 pw) {
    uint4 bA0[4], bA1[4], bB0[4], bB1[4];   // static-indexed (no scratch)
#define CPC_PREF(K, CTRL)                                                     \
    {                                                                         \
        int ia_ = DPP_I(ja, CTRL), ib_ = DPP_I(jb, CTRL);                     \
        bA0[K] = ni4[(size_t)ia_ * 8 + s];                                    \
        bA1[K] = ni4[(size_t)ia_ * 8 + 4 + s];                                \
        bB0[K] = ni4[(size_t)ib_ * 8 + s];                                    \
        bB1[K] = ni4[(size_t)ib_ * 8 + 4 + s];                                \
    }
    // prefetch iters 0,1 -- latency hides under the setup chain below
    CPC_PREF(0, 0x00)
    CPC_PREF(1, 0x55)

    float4 v = make_float4((float)hv.x, (float)hv.y, (float)hv.z, (float)hv.w);
    float sq = v.x * v.x + v.y * v.y + v.z * v.z + v.w * v.w;
    sq += FDPP_XOR1(sq);
    sq += FDPP_XOR2(sq);
    sq += __shfl_xor(sq, 4, 64);
    sq += __shfl_xor(sq, 8, 64);
    sq += __shfl_xor(sq, 16, 64);
    sq += __shfl_xor(sq, 32, 64);
    float inv = 1.0f / fmaxf(sqrtf(sq), 1e-12f);
    v.x *= inv; v.y *= inv; v.z *= inv; v.w *= inv;
    reinterpret_cast<unsigned short*>(zq)[lane] =
        (unsigned short)q4x4(v.x, v.y, v.z, v.w);
    float pd = dot2(pw.y, packh2(v.z, v.w), dot2(pw.x, packh2(v.x, v.y), 0.0f));
    uint4 zsa = zq[s];       // lane's int4 z_pred slices (LDS, same-wave RAW)
    uint4 zsb = zq[4 + s];

    float sl = 0.0f;
#define CPC_COMP(K)                                                           \
    {                                                                         \
        int aa = 0, ab = 0;                                                   \
        aa = sdot8(bA0[K].x, zsa.x, aa); aa = sdot8(bA0[K].y, zsa.y, aa);     \
        aa = sdot8(bA0[K].z, zsa.z, aa); aa = sdot8(bA0[K].w, zsa.w, aa);     \
        aa = sdot8(bA1[K].x, zsb.x, aa); aa = sdot8(bA1[K].y, zsb.y, aa);     \
        aa = sdot8(bA1[K].z, zsb.z, aa); aa = sdot8(bA1[K].w, zsb.w, aa);     \
        ab = sdot8(bB0[K].x, zsa.x, ab); ab = sdot8(bB0[K].y, zsa.y, ab);     \
        ab = sdot8(bB0[K].z, zsa.z, ab); ab = sdot8(bB0[K].w, zsa.w, ab);     \
        ab = sdot8(bB1[K].x, zsb.x, ab); ab = sdot8(bB1[K].y, zsb.y, ab);     \
        ab = sdot8(bB1[K].z, zsb.z, ab); ab = sdot8(bB1[K].w, zsb.w, ab);     \
        unsigned pk = ((unsigned)(aa + 4096) << 16) | (unsigned)(ab + 4096);  \
        pk += (unsigned)DPP_I((int)pk, 0xB1);                                 \
        pk += (unsigned)DPP_I((int)pk, 0x4E);                                 \
        float la = (float)((int)(pk >> 16) - 16384);                          \
        float lb = (float)((int)(pk & 0xffffu) - 16384);                      \
        sl += __expf(la * QSCALE4 - FMAXL) + __expf(lb * QSCALE4 - FMAXL);    \
    }
    CPC_PREF(2, 0xAA)
    CPC_COMP(0)
    CPC_PREF(3, 0xFF)
    CPC_COMP(1)
    CPC_COMP(2)
    CPC_COMP(3)
#undef CPC_PREF
#undef CPC_COMP

    // sum the 16 group values (each quad holds one distinct sl)
    sl += __shfl_xor(sl, 4, 64);
    sl += __shfl_xor(sl, 8, 64);
    sl += __shfl_xor(sl, 16, 64);
    sl += __shfl_xor(sl, 32, 64);
    // positive-logit reduction (off the loop's critical path)
    pd += FDPP_XOR1(pd);
    pd += FDPP_XOR2(pd);
    pd += __shfl_xor(pd, 4, 64);
    pd += __shfl_xor(pd, 8, 64);
    pd += __shfl_xor(pd, 16, 64);
    pd += __shfl_xor(pd, 32, 64);
    float pos = pd * TEMP_INV;
    float S = sl + __expf(pos - FMAXL);
    return FMAXL + __logf(S) - pos;
}

// TWO rows per wave (8 per block). DIAGNOSTIC: body repeated 4x (rolled loop,
// memory clobber forces re-execution; contrib overwritten each rep -> output
// bit-identical to 1 rep). Divide observed dispatch duration by 4.
__global__ __launch_bounds__(256, 4) void k_loss(const unsigned* __restrict__ az,
                                                 const unsigned* __restrict__ ani4,
                                                 const _Float16* __restrict__ zp_base,
                                                 const int* __restrict__ nx_base,
                                                 float* __restrict__ partials,
                                                 HP3 P) {
    HP hp = P.h[blockIdx.y];
    __shared__ uint4 zqm[4][8];      // per-wave int4 z_pred row (128 B)
    __shared__ float partial[4];
    int wid = threadIdx.x >> 6, lane = threadIdx.x & 63;
    int g = lane >> 2, s = lane & 3;
    int n0 = blockIdx.x * 8 + wid * 2;      // rows n0, n0+1 (hp.N is even)
    float contrib = 0.0f;
#pragma unroll 1
    for (int rep = 0; rep < 4; ++rep) {
        asm volatile("" ::: "memory");   // force genuine re-execution per rep
        if (n0 < hp.N) {
            const int* nx = nx_base + hp.nxOff + (size_t)n0 * NNEGc;
            // lane (g,s) owns iter s's negatives 32s+g, 32s+16+g
            int ja0 = nx[32 * s + g];
            int jb0 = nx[32 * s + 16 + g];
            int ja1 = nx[NNEGc + 32 * s + g];
            int jb1 = nx[NNEGc + 32 * s + 16 + g];
            const uint4* ni4 = reinterpret_cast<const uint4*>(ani4);

            // setup loads for BOTH rows, issued before any compute
            int b0 = n0 / hp.L, l0 = n0 - b0 * hp.L;
            int row0 = b0 * Tc + l0;
            int n1 = n0 + 1;
            int b1 = n1 / hp.L, l1 = n1 - b1 * hp.L;
            int row1 = b1 * Tc + l1;
            const f16x4* zph = reinterpret_cast<const f16x4*>(
                                   zp_base + (size_t)blockIdx.y * BTc * Dc);
            f16x4 hv0 = zph[(size_t)row0 * 64 + lane];
            f16x4 hv1 = zph[(size_t)row1 * 64 + lane];
            uint2 pw0 = reinterpret_cast<const uint2*>(az + (size_t)(row0 + hp.kh) * 128)[lane];
            uint2 pw1 = reinterpret_cast<const uint2*>(az + (size_t)(row1 + hp.kh) * 128)[lane];

            float c0 = row_loss(ni4, zqm[wid], lane, s, ja0, jb0, hv0, pw0);
            float c1 = row_loss(ni4, zqm[wid], lane, s, ja1, jb1, hv1, pw1);
            contrib = (c0 + c1) * hp.scale;   // overwrite (not accumulate)
        }
    }
    if (lane == 0) partial[wid] = contrib;
    __syncthreads();
    if (threadIdx.x == 0)
        partials[blockIdx.y * GXL + blockIdx.x] =
            partial[0] + partial[1] + partial[2] + partial[3];
}

// Single-block deterministic reduction of NPART partials -> out[0].
__global__ __launch_bounds__(256) void k_final(const float* __restrict__ partials,
                                               float* __restrict__ out) {
    __shared__ float ws[4];
    int wid = threadIdx.x >> 6, lane = threadIdx.x & 63;
    float s = 0.0f;
    for (int i = threadIdx.x; i < NPART; i += 256) s += partials[i];
#pragma unroll
    for (int off = 32; off; off >>= 1) s += __shfl_xor(s, off, 64);
    if (lane == 0) ws[wid] = s;
    __syncthreads();
    if (threadIdx.x == 0) out[0] = ws[0] + ws[1] + ws[2] + ws[3];
}

extern "C" void kernel_launch(void* const* d_in, const int* in_sizes, int n_in,
                              void* d_out, int out_size, void* d_ws, size_t ws_size,
                              hipStream_t stream) {
    const float* z     = (const float*)d_in[0];
    const float* preds = (const float*)d_in[1];
    const int*   nidx  = (const int*)d_in[2];
    float* out = (float*)d_out;

    unsigned*       az   = (unsigned*)d_ws;                                  // 4 MB
    unsigned short* ani4 = (unsigned short*)((char*)d_ws + (size_t)4194304); // 1 MB
    unsigned*       Wh   = (unsigned*)((char*)d_ws + (size_t)5242880);       // 384 KB
    _Float16*       zp   = (_Float16*)((char*)d_ws + (size_t)5636096);       // 12 MB
    float*          part = (float*)((char*)d_ws + (size_t)18219008);         // 24 KB

    const int ks[3] = {1, 5, 21};
    double rw[3] = {1.0, 1.0 / sqrt(5.0), 1.0 / sqrt(21.0)};
    double tot = rw[0] + rw[1] + rw[2];

    HP3 P;
    for (int i = 0; i < 3; ++i) {
        int L = Tc - ks[i], N = Bc * L;
        P.h[i].L = L; P.h[i].N = N; P.h[i].kh = ks[i];
        P.h[i].scale = (float)(rw[i] / tot / (double)N);
        P.h[i].nxOff = (long long)i * BTc * NNEGc;
    }

    k_norm<<<BTc / 4, 256, 0, stream>>>(z, preds, az, ani4, Wh);
    k_gemm<<<dim3(BTc / 64, (3 * Dc) / 64), 256, 0, stream>>>(az, Wh, zp);
    k_loss<<<dim3(GXL, 3), 256, 0, stream>>>(az, (const unsigned*)ani4, zp, nidx, part, P);
    k_final<<<1, 256, 0, stream>>>(part, out);
}

// Round 8
// 112.167 us; speedup vs baseline: 1.4181x; 1.4181x over previous
//
#include <hip/hip_runtime.h>
#include <math.h>

// CPC loss, MI355X. B=16 T=512 D=256, horizons {1,5,21}, 128 negatives, temp 0.07.
// 5 dispatches: norm -> gemm -> prep -> loss -> final.
// r7 diagnostic: k_loss warm rep 18.3us (VALUBusy 54%), cold 37us (L2 evicted
// by harness fill each iter). This round hoists the per-row setup (normalize,
// int4-quantize, pos-logit: ~40 dependent VALU + LDS RAW on the critical path)
// into k_prep, a streaming pre-pass. Bit-identical op order -> same absmax.
// ws: [0,4MB) az f16 | [4MB,+1MB) ani4 int4 | [5MB,+384KB) Wh f16 |
//     [5.375MB,+12MB) zp f16 | [17.375MB,+3MB) zq4 int4 | +96KB pos f32 |
//     +24KB partials
// LESSON (r4/r5): one agent-scope done-counter atomic per block serializes
// retirement (~30ns/RMW). LESSON (r3): spin grid barriers idle the GPU.
// LESSON (r7): harness fill (~45us, 268MB) is inside the timed window.
constexpr int Bc = 16, Tc = 512, Dc = 256, NNEGc = 128, BTc = Bc * Tc;
constexpr float TEMP_INV = 1.0f / 0.07f;
constexpr float SCALE4 = 21.875f;              // 7 / 0.32 clip
constexpr float QSCALE4 = TEMP_INV / (SCALE4 * SCALE4);
constexpr float FMAXL = TEMP_INV;              // algebraic softmax stabilizer
constexpr int GXL = 1022;                      // 8176/8 row-groups per horizon
constexpr int NPART = 3 * GXL;                 // 3066 partials

typedef __attribute__((ext_vector_type(8))) short short8;
typedef __attribute__((ext_vector_type(4))) float f32x4;
typedef __attribute__((ext_vector_type(4))) _Float16 f16x4;
typedef __attribute__((ext_vector_type(2))) _Float16 h2;

struct HP { int L, N, kh; float scale; long long nxOff; };
struct HP3 { HP h[3]; };

// DPP helpers (ctrl literal). quad_perm: xor1=0xB1, xor2=0x4E, bcast k=k*0x55.
#define DPP_I(x, ctrl) __builtin_amdgcn_update_dpp(0, (x), (ctrl), 0xF, 0xF, true)
#define FDPP_XOR1(x) __builtin_bit_cast(float, DPP_I(__builtin_bit_cast(int, (x)), 0xB1))
#define FDPP_XOR2(x) __builtin_bit_cast(float, DPP_I(__builtin_bit_cast(int, (x)), 0x4E))

__device__ inline unsigned packh2(float a, float b) {
    h2 p = {(_Float16)a, (_Float16)b};
    return __builtin_bit_cast(unsigned, p);
}
__device__ inline float dot2(unsigned a, unsigned b, float c) {
#if __has_builtin(__builtin_amdgcn_fdot2)
    return __builtin_amdgcn_fdot2(__builtin_bit_cast(h2, a), __builtin_bit_cast(h2, b), c, false);
#else
    h2 x = __builtin_bit_cast(h2, a), y = __builtin_bit_cast(h2, b);
    return c + (float)x.x * (float)y.x + (float)x.y * (float)y.y;
#endif
}
__device__ inline int sdot8(unsigned a, unsigned b, int c) {
#if __has_builtin(__builtin_amdgcn_sdot8)
    return __builtin_amdgcn_sdot8((int)a, (int)b, c, false);
#else
#pragma unroll
    for (int i = 0; i < 8; ++i) {
        int xa = ((int)(a << (28 - 4 * i))) >> 28;
        int xb = ((int)(b << (28 - 4 * i))) >> 28;
        c += xa * xb;
    }
    return c;
#endif
}
// 4 floats -> 4 signed int4 nibbles (clipped to +-7), packed low-nibble-first
__device__ inline unsigned q4x4(float a, float b, float c, float d) {
    int qa = (int)rintf(fminf(fmaxf(a * SCALE4, -7.0f), 7.0f));
    int qb = (int)rintf(fminf(fmaxf(b * SCALE4, -7.0f), 7.0f));
    int qc = (int)rintf(fminf(fmaxf(c * SCALE4, -7.0f), 7.0f));
    int qd = (int)rintf(fminf(fmaxf(d * SCALE4, -7.0f), 7.0f));
    return (qa & 0xF) | ((qb & 0xF) << 4) | ((qc & 0xF) << 8) | ((qd & 0xF) << 12);
}

// Normalize all BT rows -> az (f16, 512 B/row) + ani4 (int4, 128 B/row);
// first 96 blocks convert W to f16.
__global__ __launch_bounds__(256) void k_norm(const float* __restrict__ z,
                                              const float* __restrict__ preds,
                                              unsigned* __restrict__ az,
                                              unsigned short* __restrict__ ani4,
                                              unsigned* __restrict__ Wh) {
    if (blockIdx.x < 96) {
        int base = blockIdx.x * 2048 + threadIdx.x * 8;
        float4 w0 = reinterpret_cast<const float4*>(preds + base)[0];
        float4 w1 = reinterpret_cast<const float4*>(preds + base)[1];
        uint4 o;
        o.x = packh2(w0.x, w0.y); o.y = packh2(w0.z, w0.w);
        o.z = packh2(w1.x, w1.y); o.w = packh2(w1.z, w1.w);
        reinterpret_cast<uint4*>(Wh)[blockIdx.x * 256 + threadIdx.x] = o;
    }
    int wid = threadIdx.x >> 6, lane = threadIdx.x & 63;
    int row = blockIdx.x * 4 + wid;
    float4 v = reinterpret_cast<const float4*>(z)[row * 64 + lane];
    float s = v.x * v.x + v.y * v.y + v.z * v.z + v.w * v.w;
#pragma unroll
    for (int off = 32; off; off >>= 1) s += __shfl_xor(s, off, 64);
    float inv = 1.0f / fmaxf(sqrtf(s), 1e-12f);
    float a = v.x * inv, b = v.y * inv, c = v.z * inv, d = v.w * inv;
    reinterpret_cast<uint2*>(az)[row * 64 + lane] = make_uint2(packh2(a, b), packh2(c, d));
    ani4[row * 64 + lane] = (unsigned short)q4x4(a, b, c, d);
}

// LDS-tiled f16 MFMA GEMM, XOR-swizzled LDS. Block 64x64, K=256, 4 waves.
__global__ __launch_bounds__(256) void k_gemm(const unsigned* __restrict__ az,
                                              const unsigned* __restrict__ Wh,
                                              _Float16* __restrict__ zp) {
    __shared__ uint4 As[2048];
    __shared__ uint4 Bs[2048];
    int wave = threadIdx.x >> 6, lane = threadIdx.x & 63;
    int t = threadIdx.x;
    int m0 = blockIdx.x * 64, g0 = blockIdx.y * 64;
    const uint4* A4 = reinterpret_cast<const uint4*>(az) + (size_t)m0 * 32;
    const uint4* B4 = reinterpret_cast<const uint4*>(Wh) + (size_t)g0 * 32;
#pragma unroll
    for (int i = 0; i < 8; ++i) {
        int f = i * 256 + t;
        int r = f >> 5, c = f & 31;
        int sw = r * 32 + ((c ^ r) & 31);
        As[sw] = A4[f];
        Bs[sw] = B4[f];
    }
    __syncthreads();
    int mrow = lane & 15, kq = lane >> 4;
    f32x4 acc[4] = {f32x4{0,0,0,0}, f32x4{0,0,0,0}, f32x4{0,0,0,0}, f32x4{0,0,0,0}};
    int arow = wave * 16 + mrow;
#pragma unroll
    for (int kb = 0; kb < 8; ++kb) {
        int col = kb * 4 + kq;
        uint4 ua = As[arow * 32 + ((col ^ arow) & 31)];
        short8 a = __builtin_bit_cast(short8, ua);
#pragma unroll
        for (int nt = 0; nt < 4; ++nt) {
            int brow = nt * 16 + mrow;
            uint4 ub = Bs[brow * 32 + ((col ^ brow) & 31)];
            acc[nt] = __builtin_amdgcn_mfma_f32_16x16x32_f16(
                a, __builtin_bit_cast(short8, ub), acc[nt], 0, 0, 0);
        }
    }
#pragma unroll
    for (int nt = 0; nt < 4; ++nt) {
        int g = g0 + nt * 16 + mrow;
        int h = g >> 8, e = g & 255;
        _Float16* dst = zp + ((size_t)h * BTc + m0 + wave * 16 + kq * 4) * Dc + e;
#pragma unroll
        for (int r = 0; r < 4; ++r) dst[(size_t)r * Dc] = (_Float16)acc[nt][r];
    }
}

// Streaming pre-pass: per (horizon, row) normalize the f16 z_pred row, quantize
// to int4 (zq4: 128 B/row, layout = ushort per lane, identical to the old LDS
// zqm), and precompute the positive logit (pos). Identical op order to the old
// in-k_loss setup -> bit-identical results. One wave per row, 4 rows/block.
__global__ __launch_bounds__(256) void k_prep(const unsigned* __restrict__ az,
                                              const _Float16* __restrict__ zp_base,
                                              unsigned short* __restrict__ zq4,
                                              float* __restrict__ pos,
                                              HP3 P) {
    int wid = threadIdx.x >> 6, lane = threadIdx.x & 63;
    int R = blockIdx.x * 4 + wid;          // 0..24575
    int h = R >> 13;                       // /BTc
    int m = R & (BTc - 1);                 // row b*Tc+l
    HP hp = P.h[h];
    int l = m & (Tc - 1);
    if (l + hp.kh >= Tc) return;           // row unused for this horizon
    f16x4 hv = reinterpret_cast<const f16x4*>(
                   zp_base + ((size_t)h * BTc + m) * Dc)[lane];
    uint2 pw = reinterpret_cast<const uint2*>(az + (size_t)(m + hp.kh) * 128)[lane];
    float4 v = make_float4((float)hv.x, (float)hv.y, (float)hv.z, (float)hv.w);
    float sq = v.x * v.x + v.y * v.y + v.z * v.z + v.w * v.w;
    sq += FDPP_XOR1(sq);
    sq += FDPP_XOR2(sq);
    sq += __shfl_xor(sq, 4, 64);
    sq += __shfl_xor(sq, 8, 64);
    sq += __shfl_xor(sq, 16, 64);
    sq += __shfl_xor(sq, 32, 64);
    float inv = 1.0f / fmaxf(sqrtf(sq), 1e-12f);
    v.x *= inv; v.y *= inv; v.z *= inv; v.w *= inv;
    zq4[((size_t)h * BTc + m) * 64 + lane] = (unsigned short)q4x4(v.x, v.y, v.z, v.w);
    float pd = dot2(pw.y, packh2(v.z, v.w), dot2(pw.x, packh2(v.x, v.y), 0.0f));
    pd += FDPP_XOR1(pd);
    pd += FDPP_XOR2(pd);
    pd += __shfl_xor(pd, 4, 64);
    pd += __shfl_xor(pd, 8, 64);
    pd += __shfl_xor(pd, 16, 64);
    pd += __shfl_xor(pd, 32, 64);
    if (lane == 0) pos[h * BTc + m] = pd * TEMP_INV;
}

// Slim per-row body: 4-lane-group INT4 gather (16 gather instrs/row, every
// 64 B line fully consumed), DPP quad reductions, packed dual-logit word
// (integer-exact: per-lane field [960,7232], 4-lane sum <= 28928 < 2^16,
// bias totals 16384). No LDS, no normalize -- zq slices come in preloaded.
__device__ __forceinline__ float row_dots(const uint4* __restrict__ ni4,
                                          int s, int ja, int jb,
                                          uint4 zsa, uint4 zsb, float pos) {
    uint4 bA0[4], bA1[4], bB0[4], bB1[4];   // static-indexed (no scratch)
#define CPC_PREF(K, CTRL)                                                     \
    {                                                                         \
        int ia_ = DPP_I(ja, CTRL), ib_ = DPP_I(jb, CTRL);                     \
        bA0[K] = ni4[(size_t)ia_ * 8 + s];                                    \
        bA1[K] = ni4[(size_t)ia_ * 8 + 4 + s];                                \
        bB0[K] = ni4[(size_t)ib_ * 8 + s];                                    \
        bB1[K] = ni4[(size_t)ib_ * 8 + 4 + s];                                \
    }
    CPC_PREF(0, 0x00)
    CPC_PREF(1, 0x55)
    float sl = 0.0f;
#define CPC_COMP(K)                                                           \
    {                                                                         \
        int aa = 0, ab = 0;                                                   \
        aa = sdot8(bA0[K].x, zsa.x, aa); aa = sdot8(bA0[K].y, zsa.y, aa);     \
        aa = sdot8(bA0[K].z, zsa.z, aa); aa = sdot8(bA0[K].w, zsa.w, aa);     \
        aa = sdot8(bA1[K].x, zsb.x, aa); aa = sdot8(bA1[K].y, zsb.y, aa);     \
        aa = sdot8(bA1[K].z, zsb.z, aa); aa = sdot8(bA1[K].w, zsb.w, aa);     \
        ab = sdot8(bB0[K].x, zsa.x, ab); ab = sdot8(bB0[K].y, zsa.y, ab);     \
        ab = sdot8(bB0[K].z, zsa.z, ab); ab = sdot8(bB0[K].w, zsa.w, ab);     \
        ab = sdot8(bB1[K].x, zsb.x, ab); ab = sdot8(bB1[K].y, zsb.y, ab);     \
        ab = sdot8(bB1[K].z, zsb.z, ab); ab = sdot8(bB1[K].w, zsb.w, ab);     \
        unsigned pk = ((unsigned)(aa + 4096) << 16) | (unsigned)(ab + 4096);  \
        pk += (unsigned)DPP_I((int)pk, 0xB1);                                 \
        pk += (unsigned)DPP_I((int)pk, 0x4E);                                 \
        float la = (float)((int)(pk >> 16) - 16384);                          \
        float lb = (float)((int)(pk & 0xffffu) - 16384);                      \
        sl += __expf(la * QSCALE4 - FMAXL) + __expf(lb * QSCALE4 - FMAXL);    \
    }
    CPC_PREF(2, 0xAA)
    CPC_COMP(0)
    CPC_PREF(3, 0xFF)
    CPC_COMP(1)
    CPC_COMP(2)
    CPC_COMP(3)
#undef CPC_PREF
#undef CPC_COMP
    // sum the 16 group values (each quad holds one distinct sl)
    sl += __shfl_xor(sl, 4, 64);
    sl += __shfl_xor(sl, 8, 64);
    sl += __shfl_xor(sl, 16, 64);
    sl += __shfl_xor(sl, 32, 64);
    float S = sl + __expf(pos - FMAXL);
    return FMAXL + __logf(S) - pos;
}

// TWO rows per wave (8 per block); all per-row inputs (nx, zq slices, pos)
// issued upfront so both rows' memory flies under row0's compute.
__global__ __launch_bounds__(256, 4) void k_loss(const unsigned short* __restrict__ zq4,
                                                 const unsigned* __restrict__ ani4,
                                                 const float* __restrict__ pos,
                                                 const int* __restrict__ nx_base,
                                                 float* __restrict__ partials,
                                                 HP3 P) {
    HP hp = P.h[blockIdx.y];
    __shared__ float partial[4];
    int wid = threadIdx.x >> 6, lane = threadIdx.x & 63;
    int g = lane >> 2, s = lane & 3;
    int n0 = blockIdx.x * 8 + wid * 2;      // rows n0, n0+1 (hp.N is even)
    float contrib = 0.0f;
    if (n0 < hp.N) {
        const int* nx = nx_base + hp.nxOff + (size_t)n0 * NNEGc;
        // lane (g,s) owns iter s's negatives 32s+g, 32s+16+g (per row)
        int ja0 = nx[32 * s + g];
        int jb0 = nx[32 * s + 16 + g];
        int ja1 = nx[NNEGc + 32 * s + g];
        int jb1 = nx[NNEGc + 32 * s + 16 + g];
        const uint4* ni4 = reinterpret_cast<const uint4*>(ani4);

        int b0 = n0 / hp.L, l0 = n0 - b0 * hp.L;
        int row0 = b0 * Tc + l0;
        int n1 = n0 + 1;
        int b1 = n1 / hp.L, l1 = n1 - b1 * hp.L;
        int row1 = b1 * Tc + l1;

        const uint4* zr0 = reinterpret_cast<const uint4*>(
                               zq4 + ((size_t)blockIdx.y * BTc + row0) * 64);
        const uint4* zr1 = reinterpret_cast<const uint4*>(
                               zq4 + ((size_t)blockIdx.y * BTc + row1) * 64);
        uint4 zsa0 = zr0[s], zsb0 = zr0[4 + s];
        uint4 zsa1 = zr1[s], zsb1 = zr1[4 + s];
        float pos0 = pos[blockIdx.y * BTc + row0];
        float pos1 = pos[blockIdx.y * BTc + row1];

        float c0 = row_dots(ni4, s, ja0, jb0, zsa0, zsb0, pos0);
        float c1 = row_dots(ni4, s, ja1, jb1, zsa1, zsb1, pos1);
        contrib = (c0 + c1) * hp.scale;
    }
    if (lane == 0) partial[wid] = contrib;
    __syncthreads();
    if (threadIdx.x == 0)
        partials[blockIdx.y * GXL + blockIdx.x] =
            partial[0] + partial[1] + partial[2] + partial[3];
}

// Single-block deterministic reduction of NPART partials -> out[0].
__global__ __launch_bounds__(256) void k_final(const float* __restrict__ partials,
                                               float* __restrict__ out) {
    __shared__ float ws[4];
    int wid = threadIdx.x >> 6, lane = threadIdx.x & 63;
    float s = 0.0f;
    for (int i = threadIdx.x; i < NPART; i += 256) s += partials[i];
#pragma unroll
    for (int off = 32; off; off >>= 1) s += __shfl_xor(s, off, 64);
    if (lane == 0) ws[wid] = s;
    __syncthreads();
    if (threadIdx.x == 0) out[0] = ws[0] + ws[1] + ws[2] + ws[3];
}

extern "C" void kernel_launch(void* const* d_in, const int* in_sizes, int n_in,
                              void* d_out, int out_size, void* d_ws, size_t ws_size,
                              hipStream_t stream) {
    const float* z     = (const float*)d_in[0];
    const float* preds = (const float*)d_in[1];
    const int*   nidx  = (const int*)d_in[2];
    float* out = (float*)d_out;

    unsigned*       az   = (unsigned*)d_ws;                                   // 4 MB
    unsigned short* ani4 = (unsigned short*)((char*)d_ws + (size_t)4194304);  // 1 MB
    unsigned*       Wh   = (unsigned*)((char*)d_ws + (size_t)5242880);        // 384 KB
    _Float16*       zp   = (_Float16*)((char*)d_ws + (size_t)5636096);        // 12 MB
    unsigned short* zq4  = (unsigned short*)((char*)d_ws + (size_t)18219008); // 3 MB
    float*          pos  = (float*)((char*)d_ws + (size_t)21364736);          // 96 KB
    float*          part = (float*)((char*)d_ws + (size_t)21463040);          // 12 KB

    const int ks[3] = {1, 5, 21};
    double rw[3] = {1.0, 1.0 / sqrt(5.0), 1.0 / sqrt(21.0)};
    double tot = rw[0] + rw[1] + rw[2];

    HP3 P;
    for (int i = 0; i < 3; ++i) {
        int L = Tc - ks[i], N = Bc * L;
        P.h[i].L = L; P.h[i].N = N; P.h[i].kh = ks[i];
        P.h[i].scale = (float)(rw[i] / tot / (double)N);
        P.h[i].nxOff = (long long)i * BTc * NNEGc;
    }

    k_norm<<<BTc / 4, 256, 0, stream>>>(z, preds, az, ani4, Wh);
    k_gemm<<<dim3(BTc / 64, (3 * Dc) / 64), 256, 0, stream>>>(az, Wh, zp);
    k_prep<<<3 * BTc / 4, 256, 0, stream>>>(az, zp, zq4, pos, P);
    k_loss<<<dim3(GXL, 3), 256, 0, stream>>>(zq4, (const unsigned*)ani4, pos, nidx, part, P);
    k_final<<<1, 256, 0, stream>>>(part, out);
}

// Round 9
// 107.726 us; speedup vs baseline: 1.4765x; 1.0412x over previous
//
#include <hip/hip_runtime.h>
#include <math.h>

// CPC loss, MI355X. B=16 T=512 D=256, horizons {1,5,21}, 128 negatives, temp 0.07.
// 4 dispatches: norm -> gemm -> loss -> final   (r6 structure, best = 104.3us).
// THIS ROUND: k_loss workgroup 256->128 (occupancy packing lever; r7 measured
// 38% occupancy with no resource cap -> test finer block granularity).
// ws: [0,4MB) az f16 | [4MB,+1MB) ani4 int4 | [5MB,+384KB) Wh f16 |
//     [5.375MB,+12MB) zp f16 | [17.375MB,+24KB) partials f32
// LESSONS: r4/r5 one hot done-counter line serializes retirement (~185us).
// r3: spin grid barriers idle the GPU. r7: fill (~44us) is inside the timed
// window; k_loss warm 18us / cold 37us. r8: k_loss setup VALU was free
// (hidden under gather latency); an extra dispatch costs ~8us.
constexpr int Bc = 16, Tc = 512, Dc = 256, NNEGc = 128, BTc = Bc * Tc;
constexpr float TEMP_INV = 1.0f / 0.07f;
constexpr float SCALE4 = 21.875f;              // 7 / 0.32 clip
constexpr float QSCALE4 = TEMP_INV / (SCALE4 * SCALE4);
constexpr float FMAXL = TEMP_INV;              // algebraic softmax stabilizer
constexpr int GXL = 2044;                      // 8176/4 row-groups per horizon
constexpr int NPART = 3 * GXL;                 // 6132 partials

typedef __attribute__((ext_vector_type(8))) short short8;
typedef __attribute__((ext_vector_type(4))) float f32x4;
typedef __attribute__((ext_vector_type(4))) _Float16 f16x4;
typedef __attribute__((ext_vector_type(2))) _Float16 h2;

struct HP { int L, N, kh; float scale; long long nxOff; };
struct HP3 { HP h[3]; };

// DPP helpers (ctrl literal). quad_perm: xor1=0xB1, xor2=0x4E, bcast k=k*0x55.
#define DPP_I(x, ctrl) __builtin_amdgcn_update_dpp(0, (x), (ctrl), 0xF, 0xF, true)
#define FDPP_XOR1(x) __builtin_bit_cast(float, DPP_I(__builtin_bit_cast(int, (x)), 0xB1))
#define FDPP_XOR2(x) __builtin_bit_cast(float, DPP_I(__builtin_bit_cast(int, (x)), 0x4E))

__device__ inline unsigned packh2(float a, float b) {
    h2 p = {(_Float16)a, (_Float16)b};
    return __builtin_bit_cast(unsigned, p);
}
__device__ inline float dot2(unsigned a, unsigned b, float c) {
#if __has_builtin(__builtin_amdgcn_fdot2)
    return __builtin_amdgcn_fdot2(__builtin_bit_cast(h2, a), __builtin_bit_cast(h2, b), c, false);
#else
    h2 x = __builtin_bit_cast(h2, a), y = __builtin_bit_cast(h2, b);
    return c + (float)x.x * (float)y.x + (float)x.y * (float)y.y;
#endif
}
__device__ inline int sdot8(unsigned a, unsigned b, int c) {
#if __has_builtin(__builtin_amdgcn_sdot8)
    return __builtin_amdgcn_sdot8((int)a, (int)b, c, false);
#else
#pragma unroll
    for (int i = 0; i < 8; ++i) {
        int xa = ((int)(a << (28 - 4 * i))) >> 28;
        int xb = ((int)(b << (28 - 4 * i))) >> 28;
        c += xa * xb;
    }
    return c;
#endif
}
// 4 floats -> 4 signed int4 nibbles (clipped to +-7), packed low-nibble-first
__device__ inline unsigned q4x4(float a, float b, float c, float d) {
    int qa = (int)rintf(fminf(fmaxf(a * SCALE4, -7.0f), 7.0f));
    int qb = (int)rintf(fminf(fmaxf(b * SCALE4, -7.0f), 7.0f));
    int qc = (int)rintf(fminf(fmaxf(c * SCALE4, -7.0f), 7.0f));
    int qd = (int)rintf(fminf(fmaxf(d * SCALE4, -7.0f), 7.0f));
    return (qa & 0xF) | ((qb & 0xF) << 4) | ((qc & 0xF) << 8) | ((qd & 0xF) << 12);
}

// Normalize all BT rows -> az (f16, 512 B/row) + ani4 (int4, 128 B/row);
// first 96 blocks convert W to f16.
__global__ __launch_bounds__(256) void k_norm(const float* __restrict__ z,
                                              const float* __restrict__ preds,
                                              unsigned* __restrict__ az,
                                              unsigned short* __restrict__ ani4,
                                              unsigned* __restrict__ Wh) {
    if (blockIdx.x < 96) {
        int base = blockIdx.x * 2048 + threadIdx.x * 8;
        float4 w0 = reinterpret_cast<const float4*>(preds + base)[0];
        float4 w1 = reinterpret_cast<const float4*>(preds + base)[1];
        uint4 o;
        o.x = packh2(w0.x, w0.y); o.y = packh2(w0.z, w0.w);
        o.z = packh2(w1.x, w1.y); o.w = packh2(w1.z, w1.w);
        reinterpret_cast<uint4*>(Wh)[blockIdx.x * 256 + threadIdx.x] = o;
    }
    int wid = threadIdx.x >> 6, lane = threadIdx.x & 63;
    int row = blockIdx.x * 4 + wid;
    float4 v = reinterpret_cast<const float4*>(z)[row * 64 + lane];
    float s = v.x * v.x + v.y * v.y + v.z * v.z + v.w * v.w;
#pragma unroll
    for (int off = 32; off; off >>= 1) s += __shfl_xor(s, off, 64);
    float inv = 1.0f / fmaxf(sqrtf(s), 1e-12f);
    float a = v.x * inv, b = v.y * inv, c = v.z * inv, d = v.w * inv;
    reinterpret_cast<uint2*>(az)[row * 64 + lane] = make_uint2(packh2(a, b), packh2(c, d));
    ani4[row * 64 + lane] = (unsigned short)q4x4(a, b, c, d);
}

// LDS-tiled f16 MFMA GEMM, XOR-swizzled LDS. Block 64x64, K=256, 4 waves.
__global__ __launch_bounds__(256) void k_gemm(const unsigned* __restrict__ az,
                                              const unsigned* __restrict__ Wh,
                                              _Float16* __restrict__ zp) {
    __shared__ uint4 As[2048];
    __shared__ uint4 Bs[2048];
    int wave = threadIdx.x >> 6, lane = threadIdx.x & 63;
    int t = threadIdx.x;
    int m0 = blockIdx.x * 64, g0 = blockIdx.y * 64;
    const uint4* A4 = reinterpret_cast<const uint4*>(az) + (size_t)m0 * 32;
    const uint4* B4 = reinterpret_cast<const uint4*>(Wh) + (size_t)g0 * 32;
#pragma unroll
    for (int i = 0; i < 8; ++i) {
        int f = i * 256 + t;
        int r = f >> 5, c = f & 31;
        int sw = r * 32 + ((c ^ r) & 31);
        As[sw] = A4[f];
        Bs[sw] = B4[f];
    }
    __syncthreads();
    int mrow = lane & 15, kq = lane >> 4;
    f32x4 acc[4] = {f32x4{0,0,0,0}, f32x4{0,0,0,0}, f32x4{0,0,0,0}, f32x4{0,0,0,0}};
    int arow = wave * 16 + mrow;
#pragma unroll
    for (int kb = 0; kb < 8; ++kb) {
        int col = kb * 4 + kq;
        uint4 ua = As[arow * 32 + ((col ^ arow) & 31)];
        short8 a = __builtin_bit_cast(short8, ua);
#pragma unroll
        for (int nt = 0; nt < 4; ++nt) {
            int brow = nt * 16 + mrow;
            uint4 ub = Bs[brow * 32 + ((col ^ brow) & 31)];
            acc[nt] = __builtin_amdgcn_mfma_f32_16x16x32_f16(
                a, __builtin_bit_cast(short8, ub), acc[nt], 0, 0, 0);
        }
    }
#pragma unroll
    for (int nt = 0; nt < 4; ++nt) {
        int g = g0 + nt * 16 + mrow;
        int h = g >> 8, e = g & 255;
        _Float16* dst = zp + ((size_t)h * BTc + m0 + wave * 16 + kq * 4) * Dc + e;
#pragma unroll
        for (int r = 0; r < 4; ++r) dst[(size_t)r * Dc] = (_Float16)acc[nt][r];
    }
}

// Per-row loss body (inlined twice per wave). 4-lane-group INT4 gather
// (16 gather instrs/row, every 64 B line fully consumed), DPP quad reductions,
// packed dual-logit word (integer-exact: per-lane field [960,7232], 4-lane
// sum <= 28928 < 2^16, bias totals 16384).
__device__ __forceinline__ float row_loss(const uint4* __restrict__ ni4,
                                          uint4* __restrict__ zq,
                                          int lane, int s,
                                          int ja, int jb,
                                          f16x4 hv, uint2 pw) {
    uint4 bA0[4], bA1[4], bB0[4], bB1[4];   // static-indexed (no scratch)
#define CPC_PREF(K, CTRL)                                                     \
    {                                                                         \
        int ia_ = DPP_I(ja, CTRL), ib_ = DPP_I(jb, CTRL);                     \
        bA0[K] = ni4[(size_t)ia_ * 8 + s];                                    \
        bA1[K] = ni4[(size_t)ia_ * 8 + 4 + s];                                \
        bB0[K] = ni4[(size_t)ib_ * 8 + s];                                    \
        bB1[K] = ni4[(size_t)ib_ * 8 + 4 + s];                                \
    }
    // prefetch iters 0,1 -- latency hides under the setup chain below
    CPC_PREF(0, 0x00)
    CPC_PREF(1, 0x55)

    float4 v = make_float4((float)hv.x, (float)hv.y, (float)hv.z, (float)hv.w);
    float sq = v.x * v.x + v.y * v.y + v.z * v.z + v.w * v.w;
    sq += FDPP_XOR1(sq);
    sq += FDPP_XOR2(sq);
    sq += __shfl_xor(sq, 4, 64);
    sq += __shfl_xor(sq, 8, 64);
    sq += __shfl_xor(sq, 16, 64);
    sq += __shfl_xor(sq, 32, 64);
    float inv = 1.0f / fmaxf(sqrtf(sq), 1e-12f);
    v.x *= inv; v.y *= inv; v.z *= inv; v.w *= inv;
    reinterpret_cast<unsigned short*>(zq)[lane] =
        (unsigned short)q4x4(v.x, v.y, v.z, v.w);
    float pd = dot2(pw.y, packh2(v.z, v.w), dot2(pw.x, packh2(v.x, v.y), 0.0f));
    uint4 zsa = zq[s];       // lane's int4 z_pred slices (LDS, same-wave RAW)
    uint4 zsb = zq[4 + s];

    float sl = 0.0f;
#define CPC_COMP(K)                                                           \
    {                                                                         \
        int aa = 0, ab = 0;                                                   \
        aa = sdot8(bA0[K].x, zsa.x, aa); aa = sdot8(bA0[K].y, zsa.y, aa);     \
        aa = sdot8(bA0[K].z, zsa.z, aa); aa = sdot8(bA0[K].w, zsa.w, aa);     \
        aa = sdot8(bA1[K].x, zsb.x, aa); aa = sdot8(bA1[K].y, zsb.y, aa);     \
        aa = sdot8(bA1[K].z, zsb.z, aa); aa = sdot8(bA1[K].w, zsb.w, aa);     \
        ab = sdot8(bB0[K].x, zsa.x, ab); ab = sdot8(bB0[K].y, zsa.y, ab);     \
        ab = sdot8(bB0[K].z, zsa.z, ab); ab = sdot8(bB0[K].w, zsa.w, ab);     \
        ab = sdot8(bB1[K].x, zsb.x, ab); ab = sdot8(bB1[K].y, zsb.y, ab);     \
        ab = sdot8(bB1[K].z, zsb.z, ab); ab = sdot8(bB1[K].w, zsb.w, ab);     \
        unsigned pk = ((unsigned)(aa + 4096) << 16) | (unsigned)(ab + 4096);  \
        pk += (unsigned)DPP_I((int)pk, 0xB1);                                 \
        pk += (unsigned)DPP_I((int)pk, 0x4E);                                 \
        float la = (float)((int)(pk >> 16) - 16384);                          \
        float lb = (float)((int)(pk & 0xffffu) - 16384);                      \
        sl += __expf(la * QSCALE4 - FMAXL) + __expf(lb * QSCALE4 - FMAXL);    \
    }
    CPC_PREF(2, 0xAA)
    CPC_COMP(0)
    CPC_PREF(3, 0xFF)
    CPC_COMP(1)
    CPC_COMP(2)
    CPC_COMP(3)
#undef CPC_PREF
#undef CPC_COMP

    // sum the 16 group values (each quad holds one distinct sl)
    sl += __shfl_xor(sl, 4, 64);
    sl += __shfl_xor(sl, 8, 64);
    sl += __shfl_xor(sl, 16, 64);
    sl += __shfl_xor(sl, 32, 64);
    // positive-logit reduction (off the loop's critical path)
    pd += FDPP_XOR1(pd);
    pd += FDPP_XOR2(pd);
    pd += __shfl_xor(pd, 4, 64);
    pd += __shfl_xor(pd, 8, 64);
    pd += __shfl_xor(pd, 16, 64);
    pd += __shfl_xor(pd, 32, 64);
    float pos = pd * TEMP_INV;
    float S = sl + __expf(pos - FMAXL);
    return FMAXL + __logf(S) - pos;
}

// TWO rows per wave; 128-thread blocks (2 waves, 4 rows) for finer CU packing.
__global__ __launch_bounds__(128, 4) void k_loss(const unsigned* __restrict__ az,
                                                 const unsigned* __restrict__ ani4,
                                                 const _Float16* __restrict__ zp_base,
                                                 const int* __restrict__ nx_base,
                                                 float* __restrict__ partials,
                                                 HP3 P) {
    HP hp = P.h[blockIdx.y];
    __shared__ uint4 zqm[2][8];      // per-wave int4 z_pred row (128 B)
    __shared__ float partial[2];
    int wid = threadIdx.x >> 6, lane = threadIdx.x & 63;
    int g = lane >> 2, s = lane & 3;
    int n0 = blockIdx.x * 4 + wid * 2;      // rows n0, n0+1 (hp.N is even)
    float contrib = 0.0f;
    if (n0 < hp.N) {
        const int* nx = nx_base + hp.nxOff + (size_t)n0 * NNEGc;
        // lane (g,s) owns iter s's negatives 32s+g, 32s+16+g (per row)
        int ja0 = nx[32 * s + g];
        int jb0 = nx[32 * s + 16 + g];
        int ja1 = nx[NNEGc + 32 * s + g];
        int jb1 = nx[NNEGc + 32 * s + 16 + g];
        const uint4* ni4 = reinterpret_cast<const uint4*>(ani4);

        // setup loads for BOTH rows, issued before any compute
        int b0 = n0 / hp.L, l0 = n0 - b0 * hp.L;
        int row0 = b0 * Tc + l0;
        int n1 = n0 + 1;
        int b1 = n1 / hp.L, l1 = n1 - b1 * hp.L;
        int row1 = b1 * Tc + l1;
        const f16x4* zph = reinterpret_cast<const f16x4*>(
                               zp_base + (size_t)blockIdx.y * BTc * Dc);
        f16x4 hv0 = zph[(size_t)row0 * 64 + lane];
        f16x4 hv1 = zph[(size_t)row1 * 64 + lane];
        uint2 pw0 = reinterpret_cast<const uint2*>(az + (size_t)(row0 + hp.kh) * 128)[lane];
        uint2 pw1 = reinterpret_cast<const uint2*>(az + (size_t)(row1 + hp.kh) * 128)[lane];

        contrib  = row_loss(ni4, zqm[wid], lane, s, ja0, jb0, hv0, pw0);
        contrib += row_loss(ni4, zqm[wid], lane, s, ja1, jb1, hv1, pw1);
        contrib *= hp.scale;
    }
    if (lane == 0) partial[wid] = contrib;
    __syncthreads();
    if (threadIdx.x == 0)
        partials[blockIdx.y * GXL + blockIdx.x] = partial[0] + partial[1];
}

// Single-block deterministic reduction of NPART partials -> out[0].
__global__ __launch_bounds__(256) void k_final(const float* __restrict__ partials,
                                               float* __restrict__ out) {
    __shared__ float ws[4];
    int wid = threadIdx.x >> 6, lane = threadIdx.x & 63;
    float s = 0.0f;
    for (int i = threadIdx.x; i < NPART; i += 256) s += partials[i];
#pragma unroll
    for (int off = 32; off; off >>= 1) s += __shfl_xor(s, off, 64);
    if (lane == 0) ws[wid] = s;
    __syncthreads();
    if (threadIdx.x == 0) out[0] = ws[0] + ws[1] + ws[2] + ws[3];
}

extern "C" void kernel_launch(void* const* d_in, const int* in_sizes, int n_in,
                              void* d_out, int out_size, void* d_ws, size_t ws_size,
                              hipStream_t stream) {
    const float* z     = (const float*)d_in[0];
    const float* preds = (const float*)d_in[1];
    const int*   nidx  = (const int*)d_in[2];
    float* out = (float*)d_out;

    unsigned*       az   = (unsigned*)d_ws;                                  // 4 MB
    unsigned short* ani4 = (unsigned short*)((char*)d_ws + (size_t)4194304); // 1 MB
    unsigned*       Wh   = (unsigned*)((char*)d_ws + (size_t)5242880);       // 384 KB
    _Float16*       zp   = (_Float16*)((char*)d_ws + (size_t)5636096);       // 12 MB
    float*          part = (float*)((char*)d_ws + (size_t)18219008);         // 24 KB

    const int ks[3] = {1, 5, 21};
    double rw[3] = {1.0, 1.0 / sqrt(5.0), 1.0 / sqrt(21.0)};
    double tot = rw[0] + rw[1] + rw[2];

    HP3 P;
    for (int i = 0; i < 3; ++i) {
        int L = Tc - ks[i], N = Bc * L;
        P.h[i].L = L; P.h[i].N = N; P.h[i].kh = ks[i];
        P.h[i].scale = (float)(rw[i] / tot / (double)N);
        P.h[i].nxOff = (long long)i * BTc * NNEGc;
    }

    k_norm<<<BTc / 4, 256, 0, stream>>>(z, preds, az, ani4, Wh);
    k_gemm<<<dim3(BTc / 64, (3 * Dc) / 64), 256, 0, stream>>>(az, Wh, zp);
    k_loss<<<dim3(GXL, 3), 128, 0, stream>>>(az, (const unsigned*)ani4, zp, nidx, part, P);
    k_final<<<1, 256, 0, stream>>>(part, out);
}

// Round 10
// 103.307 us; speedup vs baseline: 1.5397x; 1.0428x over previous
//
#include <hip/hip_runtime.h>
#include <math.h>

// CPC loss, MI355X. B=16 T=512 D=256, horizons {1,5,21}, 128 negatives, temp 0.07.
// FINAL CONFIG (= round-6 verified best, 104.26us).
// 4 dispatches: norm -> gemm -> loss -> final.
// Budget (measured r7/r9): harness fill ~44us (in timed window, not ours) +
// norm 3.5 + gemm 6 + loss 37 (18 warm: VALU54%||latency; 19 cold: L3
// first-touch after fill eviction) + final/gaps ~13.
// DEAD LEVERS (all measured): DPP-vs-LDS reduce (r2: 0), fused grid-barrier
// kernel (r3: -376us, spin idles GPU), hot done-counter atomic (r4/5: -148us,
// ~30ns/RMW serialized retirement), row-pair ILP (r6: 0), setup-hoist prep
// dispatch (r8: -8us, setup VALU is FREE under gather latency), 128-thr
// occupancy packing (r9: -3.4us).
constexpr int Bc = 16, Tc = 512, Dc = 256, NNEGc = 128, BTc = Bc * Tc;
constexpr float TEMP_INV = 1.0f / 0.07f;
constexpr float SCALE4 = 21.875f;              // 7 / 0.32 clip
constexpr float QSCALE4 = TEMP_INV / (SCALE4 * SCALE4);
constexpr float FMAXL = TEMP_INV;              // algebraic softmax stabilizer
constexpr int GXL = 1022;                      // 8176/8 row-groups per horizon
constexpr int NPART = 3 * GXL;                 // 3066 partials

typedef __attribute__((ext_vector_type(8))) short short8;
typedef __attribute__((ext_vector_type(4))) float f32x4;
typedef __attribute__((ext_vector_type(4))) _Float16 f16x4;
typedef __attribute__((ext_vector_type(2))) _Float16 h2;

struct HP { int L, N, kh; float scale; long long nxOff; };
struct HP3 { HP h[3]; };

// DPP helpers (ctrl literal). quad_perm: xor1=0xB1, xor2=0x4E, bcast k=k*0x55.
#define DPP_I(x, ctrl) __builtin_amdgcn_update_dpp(0, (x), (ctrl), 0xF, 0xF, true)
#define FDPP_XOR1(x) __builtin_bit_cast(float, DPP_I(__builtin_bit_cast(int, (x)), 0xB1))
#define FDPP_XOR2(x) __builtin_bit_cast(float, DPP_I(__builtin_bit_cast(int, (x)), 0x4E))

__device__ inline unsigned packh2(float a, float b) {
    h2 p = {(_Float16)a, (_Float16)b};
    return __builtin_bit_cast(unsigned, p);
}
__device__ inline float dot2(unsigned a, unsigned b, float c) {
#if __has_builtin(__builtin_amdgcn_fdot2)
    return __builtin_amdgcn_fdot2(__builtin_bit_cast(h2, a), __builtin_bit_cast(h2, b), c, false);
#else
    h2 x = __builtin_bit_cast(h2, a), y = __builtin_bit_cast(h2, b);
    return c + (float)x.x * (float)y.x + (float)x.y * (float)y.y;
#endif
}
__device__ inline int sdot8(unsigned a, unsigned b, int c) {
#if __has_builtin(__builtin_amdgcn_sdot8)
    return __builtin_amdgcn_sdot8((int)a, (int)b, c, false);
#else
#pragma unroll
    for (int i = 0; i < 8; ++i) {
        int xa = ((int)(a << (28 - 4 * i))) >> 28;
        int xb = ((int)(b << (28 - 4 * i))) >> 28;
        c += xa * xb;
    }
    return c;
#endif
}
// 4 floats -> 4 signed int4 nibbles (clipped to +-7), packed low-nibble-first
__device__ inline unsigned q4x4(float a, float b, float c, float d) {
    int qa = (int)rintf(fminf(fmaxf(a * SCALE4, -7.0f), 7.0f));
    int qb = (int)rintf(fminf(fmaxf(b * SCALE4, -7.0f), 7.0f));
    int qc = (int)rintf(fminf(fmaxf(c * SCALE4, -7.0f), 7.0f));
    int qd = (int)rintf(fminf(fmaxf(d * SCALE4, -7.0f), 7.0f));
    return (qa & 0xF) | ((qb & 0xF) << 4) | ((qc & 0xF) << 8) | ((qd & 0xF) << 12);
}

// Normalize all BT rows -> az (f16, 512 B/row) + ani4 (int4, 128 B/row);
// first 96 blocks convert W to f16.
__global__ __launch_bounds__(256) void k_norm(const float* __restrict__ z,
                                              const float* __restrict__ preds,
                                              unsigned* __restrict__ az,
                                              unsigned short* __restrict__ ani4,
                                              unsigned* __restrict__ Wh) {
    if (blockIdx.x < 96) {
        int base = blockIdx.x * 2048 + threadIdx.x * 8;
        float4 w0 = reinterpret_cast<const float4*>(preds + base)[0];
        float4 w1 = reinterpret_cast<const float4*>(preds + base)[1];
        uint4 o;
        o.x = packh2(w0.x, w0.y); o.y = packh2(w0.z, w0.w);
        o.z = packh2(w1.x, w1.y); o.w = packh2(w1.z, w1.w);
        reinterpret_cast<uint4*>(Wh)[blockIdx.x * 256 + threadIdx.x] = o;
    }
    int wid = threadIdx.x >> 6, lane = threadIdx.x & 63;
    int row = blockIdx.x * 4 + wid;
    float4 v = reinterpret_cast<const float4*>(z)[row * 64 + lane];
    float s = v.x * v.x + v.y * v.y + v.z * v.z + v.w * v.w;
#pragma unroll
    for (int off = 32; off; off >>= 1) s += __shfl_xor(s, off, 64);
    float inv = 1.0f / fmaxf(sqrtf(s), 1e-12f);
    float a = v.x * inv, b = v.y * inv, c = v.z * inv, d = v.w * inv;
    reinterpret_cast<uint2*>(az)[row * 64 + lane] = make_uint2(packh2(a, b), packh2(c, d));
    ani4[row * 64 + lane] = (unsigned short)q4x4(a, b, c, d);
}

// LDS-tiled f16 MFMA GEMM, XOR-swizzled LDS. Block 64x64, K=256, 4 waves.
__global__ __launch_bounds__(256) void k_gemm(const unsigned* __restrict__ az,
                                              const unsigned* __restrict__ Wh,
                                              _Float16* __restrict__ zp) {
    __shared__ uint4 As[2048];
    __shared__ uint4 Bs[2048];
    int wave = threadIdx.x >> 6, lane = threadIdx.x & 63;
    int t = threadIdx.x;
    int m0 = blockIdx.x * 64, g0 = blockIdx.y * 64;
    const uint4* A4 = reinterpret_cast<const uint4*>(az) + (size_t)m0 * 32;
    const uint4* B4 = reinterpret_cast<const uint4*>(Wh) + (size_t)g0 * 32;
#pragma unroll
    for (int i = 0; i < 8; ++i) {
        int f = i * 256 + t;
        int r = f >> 5, c = f & 31;
        int sw = r * 32 + ((c ^ r) & 31);
        As[sw] = A4[f];
        Bs[sw] = B4[f];
    }
    __syncthreads();
    int mrow = lane & 15, kq = lane >> 4;
    f32x4 acc[4] = {f32x4{0,0,0,0}, f32x4{0,0,0,0}, f32x4{0,0,0,0}, f32x4{0,0,0,0}};
    int arow = wave * 16 + mrow;
#pragma unroll
    for (int kb = 0; kb < 8; ++kb) {
        int col = kb * 4 + kq;
        uint4 ua = As[arow * 32 + ((col ^ arow) & 31)];
        short8 a = __builtin_bit_cast(short8, ua);
#pragma unroll
        for (int nt = 0; nt < 4; ++nt) {
            int brow = nt * 16 + mrow;
            uint4 ub = Bs[brow * 32 + ((col ^ brow) & 31)];
            acc[nt] = __builtin_amdgcn_mfma_f32_16x16x32_f16(
                a, __builtin_bit_cast(short8, ub), acc[nt], 0, 0, 0);
        }
    }
#pragma unroll
    for (int nt = 0; nt < 4; ++nt) {
        int g = g0 + nt * 16 + mrow;
        int h = g >> 8, e = g & 255;
        _Float16* dst = zp + ((size_t)h * BTc + m0 + wave * 16 + kq * 4) * Dc + e;
#pragma unroll
        for (int r = 0; r < 4; ++r) dst[(size_t)r * Dc] = (_Float16)acc[nt][r];
    }
}

// Per-row loss body (inlined twice per wave). 4-lane-group INT4 gather
// (16 gather instrs/row, every 64 B line fully consumed), DPP quad reductions,
// packed dual-logit word (integer-exact: per-lane field [960,7232], 4-lane
// sum <= 28928 < 2^16, bias totals 16384).
__device__ __forceinline__ float row_loss(const uint4* __restrict__ ni4,
                                          uint4* __restrict__ zq,
                                          int lane, int s,
                                          int ja, int jb,
                                          f16x4 hv, uint2 pw) {
    uint4 bA0[4], bA1[4], bB0[4], bB1[4];   // static-indexed (no scratch)
#define CPC_PREF(K, CTRL)                                                     \
    {                                                                         \
        int ia_ = DPP_I(ja, CTRL), ib_ = DPP_I(jb, CTRL);                     \
        bA0[K] = ni4[(size_t)ia_ * 8 + s];                                    \
        bA1[K] = ni4[(size_t)ia_ * 8 + 4 + s];                                \
        bB0[K] = ni4[(size_t)ib_ * 8 + s];                                    \
        bB1[K] = ni4[(size_t)ib_ * 8 + 4 + s];                                \
    }
    // prefetch iters 0,1 -- latency hides under the setup chain below
    CPC_PREF(0, 0x00)
    CPC_PREF(1, 0x55)

    float4 v = make_float4((float)hv.x, (float)hv.y, (float)hv.z, (float)hv.w);
    float sq = v.x * v.x + v.y * v.y + v.z * v.z + v.w * v.w;
    sq += FDPP_XOR1(sq);
    sq += FDPP_XOR2(sq);
    sq += __shfl_xor(sq, 4, 64);
    sq += __shfl_xor(sq, 8, 64);
    sq += __shfl_xor(sq, 16, 64);
    sq += __shfl_xor(sq, 32, 64);
    float inv = 1.0f / fmaxf(sqrtf(sq), 1e-12f);
    v.x *= inv; v.y *= inv; v.z *= inv; v.w *= inv;
    reinterpret_cast<unsigned short*>(zq)[lane] =
        (unsigned short)q4x4(v.x, v.y, v.z, v.w);
    float pd = dot2(pw.y, packh2(v.z, v.w), dot2(pw.x, packh2(v.x, v.y), 0.0f));
    uint4 zsa = zq[s];       // lane's int4 z_pred slices (LDS, same-wave RAW)
    uint4 zsb = zq[4 + s];

    float sl = 0.0f;
#define CPC_COMP(K)                                                           \
    {                                                                         \
        int aa = 0, ab = 0;                                                   \
        aa = sdot8(bA0[K].x, zsa.x, aa); aa = sdot8(bA0[K].y, zsa.y, aa);     \
        aa = sdot8(bA0[K].z, zsa.z, aa); aa = sdot8(bA0[K].w, zsa.w, aa);     \
        aa = sdot8(bA1[K].x, zsb.x, aa); aa = sdot8(bA1[K].y, zsb.y, aa);     \
        aa = sdot8(bA1[K].z, zsb.z, aa); aa = sdot8(bA1[K].w, zsb.w, aa);     \
        ab = sdot8(bB0[K].x, zsa.x, ab); ab = sdot8(bB0[K].y, zsa.y, ab);     \
        ab = sdot8(bB0[K].z, zsa.z, ab); ab = sdot8(bB0[K].w, zsa.w, ab);     \
        ab = sdot8(bB1[K].x, zsb.x, ab); ab = sdot8(bB1[K].y, zsb.y, ab);     \
        ab = sdot8(bB1[K].z, zsb.z, ab); ab = sdot8(bB1[K].w, zsb.w, ab);     \
        unsigned pk = ((unsigned)(aa + 4096) << 16) | (unsigned)(ab + 4096);  \
        pk += (unsigned)DPP_I((int)pk, 0xB1);                                 \
        pk += (unsigned)DPP_I((int)pk, 0x4E);                                 \
        float la = (float)((int)(pk >> 16) - 16384);                          \
        float lb = (float)((int)(pk & 0xffffu) - 16384);                      \
        sl += __expf(la * QSCALE4 - FMAXL) + __expf(lb * QSCALE4 - FMAXL);    \
    }
    CPC_PREF(2, 0xAA)
    CPC_COMP(0)
    CPC_PREF(3, 0xFF)
    CPC_COMP(1)
    CPC_COMP(2)
    CPC_COMP(3)
#undef CPC_PREF
#undef CPC_COMP

    // sum the 16 group values (each quad holds one distinct sl)
    sl += __shfl_xor(sl, 4, 64);
    sl += __shfl_xor(sl, 8, 64);
    sl += __shfl_xor(sl, 16, 64);
    sl += __shfl_xor(sl, 32, 64);
    // positive-logit reduction (off the loop's critical path)
    pd += FDPP_XOR1(pd);
    pd += FDPP_XOR2(pd);
    pd += __shfl_xor(pd, 4, 64);
    pd += __shfl_xor(pd, 8, 64);
    pd += __shfl_xor(pd, 16, 64);
    pd += __shfl_xor(pd, 32, 64);
    float pos = pd * TEMP_INV;
    float S = sl + __expf(pos - FMAXL);
    return FMAXL + __logf(S) - pos;
}

// TWO rows per wave (8 per block): row1's nx/zp/az loads issue at the top so
// their HBM/L2 latency hides under row0's ~2000-cycle compute; row1's gathers
// fly under row1's setup chain.
__global__ __launch_bounds__(256, 4) void k_loss(const unsigned* __restrict__ az,
                                                 const unsigned* __restrict__ ani4,
                                                 const _Float16* __restrict__ zp_base,
                                                 const int* __restrict__ nx_base,
                                                 float* __restrict__ partials,
                                                 HP3 P) {
    HP hp = P.h[blockIdx.y];
    __shared__ uint4 zqm[4][8];      // per-wave int4 z_pred row (128 B)
    __shared__ float partial[4];
    int wid = threadIdx.x >> 6, lane = threadIdx.x & 63;
    int g = lane >> 2, s = lane & 3;
    int n0 = blockIdx.x * 8 + wid * 2;      // rows n0, n0+1 (hp.N is even)
    float contrib = 0.0f;
    if (n0 < hp.N) {
        const int* nx = nx_base + hp.nxOff + (size_t)n0 * NNEGc;
        // lane (g,s) owns iter s's negatives 32s+g, 32s+16+g (per row)
        int ja0 = nx[32 * s + g];
        int jb0 = nx[32 * s + 16 + g];
        int ja1 = nx[NNEGc + 32 * s + g];
        int jb1 = nx[NNEGc + 32 * s + 16 + g];
        const uint4* ni4 = reinterpret_cast<const uint4*>(ani4);

        // setup loads for BOTH rows, issued before any compute
        int b0 = n0 / hp.L, l0 = n0 - b0 * hp.L;
        int row0 = b0 * Tc + l0;
        int n1 = n0 + 1;
        int b1 = n1 / hp.L, l1 = n1 - b1 * hp.L;
        int row1 = b1 * Tc + l1;
        const f16x4* zph = reinterpret_cast<const f16x4*>(
                               zp_base + (size_t)blockIdx.y * BTc * Dc);
        f16x4 hv0 = zph[(size_t)row0 * 64 + lane];
        f16x4 hv1 = zph[(size_t)row1 * 64 + lane];
        uint2 pw0 = reinterpret_cast<const uint2*>(az + (size_t)(row0 + hp.kh) * 128)[lane];
        uint2 pw1 = reinterpret_cast<const uint2*>(az + (size_t)(row1 + hp.kh) * 128)[lane];

        contrib  = row_loss(ni4, zqm[wid], lane, s, ja0, jb0, hv0, pw0);
        contrib += row_loss(ni4, zqm[wid], lane, s, ja1, jb1, hv1, pw1);
        contrib *= hp.scale;
    }
    if (lane == 0) partial[wid] = contrib;
    __syncthreads();
    if (threadIdx.x == 0)
        partials[blockIdx.y * GXL + blockIdx.x] =
            partial[0] + partial[1] + partial[2] + partial[3];
}

// Single-block deterministic reduction of NPART partials -> out[0].
__global__ __launch_bounds__(256) void k_final(const float* __restrict__ partials,
                                               float* __restrict__ out) {
    __shared__ float ws[4];
    int wid = threadIdx.x >> 6, lane = threadIdx.x & 63;
    float s = 0.0f;
    for (int i = threadIdx.x; i < NPART; i += 256) s += partials[i];
#pragma unroll
    for (int off = 32; off; off >>= 1) s += __shfl_xor(s, off, 64);
    if (lane == 0) ws[wid] = s;
    __syncthreads();
    if (threadIdx.x == 0) out[0] = ws[0] + ws[1] + ws[2] + ws[3];
}

extern "C" void kernel_launch(void* const* d_in, const int* in_sizes, int n_in,
                              void* d_out, int out_size, void* d_ws, size_t ws_size,
                              hipStream_t stream) {
    const float* z     = (const float*)d_in[0];
    const float* preds = (const float*)d_in[1];
    const int*   nidx  = (const int*)d_in[2];
    float* out = (float*)d_out;

    unsigned*       az   = (unsigned*)d_ws;                                  // 4 MB
    unsigned short* ani4 = (unsigned short*)((char*)d_ws + (size_t)4194304); // 1 MB
    unsigned*       Wh   = (unsigned*)((char*)d_ws + (size_t)5242880);       // 384 KB
    _Float16*       zp   = (_Float16*)((char*)d_ws + (size_t)5636096);       // 12 MB
    float*          part = (float*)((char*)d_ws + (size_t)18219008);         // 24 KB

    const int ks[3] = {1, 5, 21};
    double rw[3] = {1.0, 1.0 / sqrt(5.0), 1.0 / sqrt(21.0)};
    double tot = rw[0] + rw[1] + rw[2];

    HP3 P;
    for (int i = 0; i < 3; ++i) {
        int L = Tc - ks[i], N = Bc * L;
        P.h[i].L = L; P.h[i].N = N; P.h[i].kh = ks[i];
        P.h[i].scale = (float)(rw[i] / tot / (double)N);
        P.h[i].nxOff = (long long)i * BTc * NNEGc;
    }

    k_norm<<<BTc / 4, 256, 0, stream>>>(z, preds, az, ani4, Wh);
    k_gemm<<<dim3(BTc / 64, (3 * Dc) / 64), 256, 0, stream>>>(az, Wh, zp);
    k_loss<<<dim3(GXL, 3), 256, 0, stream>>>(az, (const unsigned*)ani4, zp, nidx, part, P);
    k_final<<<1, 256, 0, stream>>>(part, out);
}